// Round 2
// baseline (966.764 us; speedup 1.0000x reference)
//
#include <hip/hip_runtime.h>
#include <math.h>

typedef __attribute__((ext_vector_type(8))) short s16x8;   // 8 bf16 (4 VGPRs)
typedef __attribute__((ext_vector_type(4))) float f32x4;

__device__ inline ushort f2bf(float f) {
    union { float f; unsigned u; } v; v.f = f;
    unsigned r = v.u + 0x7FFF + ((v.u >> 16) & 1);   // RTN-even
    return (ushort)(r >> 16);
}
__device__ inline float bf2f(ushort h) {
    union { unsigned u; float f; } v; v.u = ((unsigned)h) << 16;
    return v.f;
}
__device__ inline float bfLo(unsigned u) {   // element at even index (low half)
    union { unsigned x; float f; } v; v.x = u << 16; return v.f;
}
__device__ inline float bfHi(unsigned u) {   // element at odd index (high half)
    union { unsigned x; float f; } v; v.x = u & 0xFFFF0000u; return v.f;
}

// ---------------- CSR build ----------------

__global__ void hist_kernel(const int* __restrict__ dst, int E, int* __restrict__ cnt) {
    int e = blockIdx.x * blockDim.x + threadIdx.x;
    if (e < E) atomicAdd(&cnt[dst[e]], 1);
}

__global__ void alloc_kernel(const int* __restrict__ cnt, int* __restrict__ row_start,
                             float* __restrict__ dinv, int* __restrict__ total, int N) {
    int i = blockIdx.x * blockDim.x + threadIdx.x;
    int lane = threadIdx.x & 63;
    int c = (i < N) ? cnt[i] : 0;
    int inc = c;
#pragma unroll
    for (int o = 1; o < 64; o <<= 1) {
        int v = __shfl_up(inc, o, 64);
        if (lane >= o) inc += v;
    }
    int wsum = __shfl(inc, 63, 64);
    int base = 0;
    if (lane == 0) base = atomicAdd(total, wsum);
    base = __shfl(base, 0, 64);
    if (i < N) {
        row_start[i] = base + inc - c;
        dinv[i] = rsqrtf((float)(c + 1));
    }
}

__global__ void scatter_kernel(const int* __restrict__ src, const int* __restrict__ dst, int E,
                               const int* __restrict__ row_start, int* __restrict__ cursor,
                               int* __restrict__ csr) {
    int e = blockIdx.x * blockDim.x + threadIdx.x;
    if (e < E) {
        int d = dst[e];
        int p = row_start[d] + atomicAdd(&cursor[d], 1);
        csr[p] = src[e];
    }
}

// ---------------- W1^T hi/lo split precompute: wt[n][k] bf16 ----------------
__global__ void wsplit_kernel(const float* __restrict__ W, ushort* __restrict__ wt_hi,
                              ushort* __restrict__ wt_lo) {
    int idx = blockIdx.x * blockDim.x + threadIdx.x;
    if (idx < 64 * 512) {
        int n = idx & 63, k = idx >> 6;           // read coalesced over n
        float f = W[k * 64 + n];
        ushort h = f2bf(f);
        wt_hi[n * 512 + k] = h;
        wt_lo[n * 512 + k] = f2bf(f - bf2f(h));
    }
}

// ---------------- W2^T hi/lo split precompute: wt2[n][k] bf16, n=0..255 k=0..63 --------
__global__ void w2split_kernel(const float* __restrict__ W, ushort* __restrict__ wt_hi,
                               ushort* __restrict__ wt_lo) {
    int idx = blockIdx.x * blockDim.x + threadIdx.x;
    if (idx < 64 * 256) {
        int n = idx & 255, k = idx >> 8;          // read coalesced over n
        float f = W[k * 256 + n];
        ushort h = f2bf(f);
        wt_hi[n * 64 + k] = h;
        wt_lo[n * 64 + k] = f2bf(f - bf2f(h));
    }
}

// ---------------- GEMM1 (MFMA): p = dinv * (x @ W1) as bf16, hi/lo 3-term split ----------
__global__ __launch_bounds__(256, 3) void gemm1_kernel(const float* __restrict__ x,
                                                       const ushort* __restrict__ wt_hi,
                                                       const ushort* __restrict__ wt_lo,
                                                       const float* __restrict__ dinv,
                                                       ushort* __restrict__ out, int N) {
    __shared__ __align__(16) short xs_hi[128 * 64];   // 16 KB  [node][g'*8+j]
    __shared__ __align__(16) short xs_lo[128 * 64];   // 16 KB
    __shared__ __align__(16) short ws_hi[64 * 64];    //  8 KB  [n][g'*8+j]
    __shared__ __align__(16) short ws_lo[64 * 64];    //  8 KB

    const int tid = threadIdx.x;
    const int nodeBase = blockIdx.x * 128;
    const int wave = tid >> 6, lane = tid & 63;
    const int m16 = lane & 15, quad = lane >> 4;

    f32x4 acc[2][4];
#pragma unroll
    for (int mt = 0; mt < 2; mt++)
#pragma unroll
        for (int nt = 0; nt < 4; nt++) acc[mt][nt] = (f32x4){0.f, 0.f, 0.f, 0.f};

    for (int kc = 0; kc < 512; kc += 64) {
        __syncthreads();
#pragma unroll
        for (int i = 0; i < 4; i++) {
            int f = tid + i * 256;            // 0..1023
            int node = f >> 3, g = f & 7;
            int gn = nodeBase + node;
            if (gn >= N) gn = N - 1;
            const float4 a = *(const float4*)(x + (size_t)gn * 512 + kc + g * 8);
            const float4 b = *(const float4*)(x + (size_t)gn * 512 + kc + g * 8 + 4);
            float ff[8] = {a.x, a.y, a.z, a.w, b.x, b.y, b.z, b.w};
            union { ushort u[8]; uint4 v; } H, L;
#pragma unroll
            for (int j = 0; j < 8; j++) {
                ushort h = f2bf(ff[j]);
                H.u[j] = h;
                L.u[j] = f2bf(ff[j] - bf2f(h));
            }
            int gp = (g + node) & 7;
            *(uint4*)&xs_hi[node * 64 + gp * 8] = H.v;
            *(uint4*)&xs_lo[node * 64 + gp * 8] = L.v;
        }
#pragma unroll
        for (int i = 0; i < 2; i++) {
            int f = tid + i * 256;            // 0..511
            int n = f >> 3, g = f & 7;
            int gp = (g + n) & 7;
            *(uint4*)&ws_hi[n * 64 + gp * 8] =
                *(const uint4*)(wt_hi + (size_t)n * 512 + kc + g * 8);
            *(uint4*)&ws_lo[n * 64 + gp * 8] =
                *(const uint4*)(wt_lo + (size_t)n * 512 + kc + g * 8);
        }
        __syncthreads();
#pragma unroll
        for (int ck = 0; ck < 2; ck++) {
            s16x8 Ah[2], Al[2];
#pragma unroll
            for (int mt = 0; mt < 2; mt++) {
                int row = (wave * 2 + mt) * 16 + m16;     // local 0..127
                int gp = (ck * 4 + quad + row) & 7;
                Ah[mt] = *(s16x8*)&xs_hi[row * 64 + gp * 8];
                Al[mt] = *(s16x8*)&xs_lo[row * 64 + gp * 8];
            }
#pragma unroll
            for (int nt = 0; nt < 4; nt++) {
                int n = nt * 16 + m16;                    // local 0..63
                int gp = (ck * 4 + quad + n) & 7;
                s16x8 Bh = *(s16x8*)&ws_hi[n * 64 + gp * 8];
                s16x8 Bl = *(s16x8*)&ws_lo[n * 64 + gp * 8];
#pragma unroll
                for (int mt = 0; mt < 2; mt++) {
                    acc[mt][nt] = __builtin_amdgcn_mfma_f32_16x16x32_bf16(Ah[mt], Bh, acc[mt][nt], 0, 0, 0);
                    acc[mt][nt] = __builtin_amdgcn_mfma_f32_16x16x32_bf16(Ah[mt], Bl, acc[mt][nt], 0, 0, 0);
                    acc[mt][nt] = __builtin_amdgcn_mfma_f32_16x16x32_bf16(Al[mt], Bh, acc[mt][nt], 0, 0, 0);
                }
            }
        }
    }
    // C/D layout: col = lane&15, row = quad*4 + reg. Write p = dinv*acc as bf16.
#pragma unroll
    for (int mt = 0; mt < 2; mt++) {
#pragma unroll
        for (int r = 0; r < 4; r++) {
            int gn = nodeBase + (wave * 2 + mt) * 16 + quad * 4 + r;
            if (gn < N) {
                float di = dinv[gn];
#pragma unroll
                for (int nt = 0; nt < 4; nt++)
                    out[(size_t)gn * 64 + nt * 16 + m16] = f2bf(di * acc[mt][nt][r]);
            }
        }
    }
}

// ---------------- 64-dim CSR aggregation, vectorized: 4 rows per wave-instruction -------
// out[i] = post( dinv[i] * (in[i] + sum_j in[j]) ), one wave per node.
// Lane layout: quad = lane>>4 handles neighbor slot e+quad; 16 lanes cover the full
// 128 B row with uint2 (4 bf16 each). Slot 0 = self loop. Two batches in flight.
template <int RELU, int BIAS, int PREMUL>
__global__ void agg64bf_kernel(const ushort* __restrict__ in, ushort* __restrict__ out,
                               const int* __restrict__ row_start, const int* __restrict__ cnt,
                               const int* __restrict__ csr, const float* __restrict__ dinv,
                               const float* __restrict__ bias, int N) {
    int gw = (int)((blockIdx.x * (size_t)blockDim.x + threadIdx.x) >> 6);
    int lane = threadIdx.x & 63;
    if (gw >= N) return;
    const int m16 = lane & 15;        // feature group: features 4*m16 .. 4*m16+3
    const int quad = lane >> 4;       // neighbor slot within the batch of 4

    const int s = row_start[gw];
    const int c = cnt[gw];
    const int total = c + 1;          // slot 0 = self, slots 1..c = neighbors

    float a0 = 0.f, a1 = 0.f, a2v = 0.f, a3 = 0.f;
    for (int e = 0; e < total; e += 8) {
        int s0 = e + quad, s1 = e + 4 + quad;
        bool v0 = s0 < total, v1 = s1 < total;
        int j0 = gw, j1 = gw;
        if (v0 && s0 > 0) j0 = csr[s + s0 - 1];
        if (v1 && s1 > 0) j1 = csr[s + s1 - 1];
        uint2 u0 = *(const uint2*)(in + (size_t)j0 * 64 + m16 * 4);
        uint2 u1 = *(const uint2*)(in + (size_t)j1 * 64 + m16 * 4);
        if (v0) { a0 += bfLo(u0.x); a1 += bfHi(u0.x); a2v += bfLo(u0.y); a3 += bfHi(u0.y); }
        if (v1) { a0 += bfLo(u1.x); a1 += bfHi(u1.x); a2v += bfLo(u1.y); a3 += bfHi(u1.y); }
    }
    // combine the 4 quads (lane ^16, ^32)
    a0 += __shfl_xor(a0, 16, 64); a0 += __shfl_xor(a0, 32, 64);
    a1 += __shfl_xor(a1, 16, 64); a1 += __shfl_xor(a1, 32, 64);
    a2v += __shfl_xor(a2v, 16, 64); a2v += __shfl_xor(a2v, 32, 64);
    a3 += __shfl_xor(a3, 16, 64); a3 += __shfl_xor(a3, 32, 64);

    float di = dinv[gw];
    float r0 = di * a0, r1 = di * a1, r2 = di * a2v, r3 = di * a3;
    if (BIAS) {
        float4 bv = *(const float4*)&bias[m16 * 4];
        r0 += bv.x; r1 += bv.y; r2 += bv.z; r3 += bv.w;
    }
    if (RELU) {
        r0 = fmaxf(r0, 0.f); r1 = fmaxf(r1, 0.f);
        r2 = fmaxf(r2, 0.f); r3 = fmaxf(r3, 0.f);
    }
    if (PREMUL) { r0 *= di; r1 *= di; r2 *= di; r3 *= di; }
    if (quad == 0) {
        uint2 o;
        o.x = ((unsigned)f2bf(r1) << 16) | f2bf(r0);
        o.y = ((unsigned)f2bf(r3) << 16) | f2bf(r2);
        *(uint2*)(out + (size_t)gw * 64 + m16 * 4) = o;
    }
}

// ---------------- fused GEMM2 (+bias,relu) + GEMM3, MFMA version ----------------
// r[i] = dinv[i] * (relu(a2[i] @ W2 + b2) @ W3)
// a2 is ALREADY bf16 (exact A operand). W2 split into bf16 hi/lo (2-term).
// Fragments loaded directly from global; no LDS, no barriers. W2^T hi/lo L2-resident.
__global__ __launch_bounds__(256, 2) void gemm23_kernel(const ushort* __restrict__ a2,
                                                        const ushort* __restrict__ wt2_hi,
                                                        const ushort* __restrict__ wt2_lo,
                                                        const float* __restrict__ b2,
                                                        const float* __restrict__ W3,
                                                        const float* __restrict__ dinv,
                                                        float* __restrict__ r, int N) {
    const int tid = threadIdx.x;
    const int wave = tid >> 6, lane = tid & 63;
    const int m16 = lane & 15, quad = lane >> 4;
    const int rowBase = blockIdx.x * 128 + wave * 32;   // wave covers 32 nodes

    // A fragments: row = rowBase + mt*16 + m16, k = ck*32 + quad*8 .. +8
    s16x8 A[2][2];
#pragma unroll
    for (int mt = 0; mt < 2; mt++) {
        int gn = rowBase + mt * 16 + m16;
        if (gn >= N) gn = N - 1;
        const ushort* ap = a2 + (size_t)gn * 64 + quad * 8;
#pragma unroll
        for (int ck = 0; ck < 2; ck++)
            A[mt][ck] = *(const s16x8*)(ap + ck * 32);
    }

    f32x4 acc[2][16];
#pragma unroll
    for (int mt = 0; mt < 2; mt++)
#pragma unroll
        for (int nt = 0; nt < 16; nt++) acc[mt][nt] = (f32x4){0.f, 0.f, 0.f, 0.f};

#pragma unroll
    for (int nt = 0; nt < 16; nt++) {
        int n = nt * 16 + m16;                           // output col 0..255
        const ushort* bh = wt2_hi + (size_t)n * 64 + quad * 8;
        const ushort* bl = wt2_lo + (size_t)n * 64 + quad * 8;
        s16x8 Bh0 = *(const s16x8*)(bh);
        s16x8 Bh1 = *(const s16x8*)(bh + 32);
        s16x8 Bl0 = *(const s16x8*)(bl);
        s16x8 Bl1 = *(const s16x8*)(bl + 32);
        acc[0][nt] = __builtin_amdgcn_mfma_f32_16x16x32_bf16(A[0][0], Bh0, acc[0][nt], 0, 0, 0);
        acc[1][nt] = __builtin_amdgcn_mfma_f32_16x16x32_bf16(A[1][0], Bh0, acc[1][nt], 0, 0, 0);
        acc[0][nt] = __builtin_amdgcn_mfma_f32_16x16x32_bf16(A[0][1], Bh1, acc[0][nt], 0, 0, 0);
        acc[1][nt] = __builtin_amdgcn_mfma_f32_16x16x32_bf16(A[1][1], Bh1, acc[1][nt], 0, 0, 0);
        acc[0][nt] = __builtin_amdgcn_mfma_f32_16x16x32_bf16(A[0][0], Bl0, acc[0][nt], 0, 0, 0);
        acc[1][nt] = __builtin_amdgcn_mfma_f32_16x16x32_bf16(A[1][0], Bl0, acc[1][nt], 0, 0, 0);
        acc[0][nt] = __builtin_amdgcn_mfma_f32_16x16x32_bf16(A[0][1], Bl1, acc[0][nt], 0, 0, 0);
        acc[1][nt] = __builtin_amdgcn_mfma_f32_16x16x32_bf16(A[1][1], Bl1, acc[1][nt], 0, 0, 0);
    }

    // epilogue: per lane holds cols {nt*16+m16} of rows {mt*16+quad*4+rr}
    float bv[16], wv[16];
#pragma unroll
    for (int nt = 0; nt < 16; nt++) {
        bv[nt] = b2[nt * 16 + m16];
        wv[nt] = W3[nt * 16 + m16];
    }
#pragma unroll
    for (int mt = 0; mt < 2; mt++) {
#pragma unroll
        for (int rr = 0; rr < 4; rr++) {
            float p = 0.f;
#pragma unroll
            for (int nt = 0; nt < 16; nt++) {
                float v = fmaxf(acc[mt][nt][rr] + bv[nt], 0.f);
                p = fmaf(v, wv[nt], p);
            }
            // reduce the 16-lane m16 group (same quad = same row)
#pragma unroll
            for (int off = 1; off < 16; off <<= 1) p += __shfl_xor(p, off, 64);
            int gn = rowBase + mt * 16 + quad * 4 + rr;
            if (m16 == 0 && gn < N) r[gn] = dinv[gn] * p;
        }
    }
}

// ---------------- wave-per-node aggregation of premultiplied r + BCE + mean -------------
__global__ void loss_kernel(const float* __restrict__ r, const float* __restrict__ dinv,
                            const int* __restrict__ row_start, const int* __restrict__ cnt,
                            const int* __restrict__ csr, const float* __restrict__ y,
                            const float* __restrict__ b3, float* __restrict__ out,
                            int N, float invN) {
    int gw = (int)((blockIdx.x * (size_t)blockDim.x + threadIdx.x) >> 6);
    int lane = threadIdx.x & 63;
    int wave = threadIdx.x >> 6;
    float loss = 0.f;
    if (gw < N) {
        int s = row_start[gw], c = cnt[gw];
        float acc = 0.f;
        for (int e = lane; e < c; e += 64) acc += r[csr[s + e]];
#pragma unroll
        for (int off = 32; off > 0; off >>= 1) acc += __shfl_xor(acc, off, 64);
        if (lane == 0) {
            float z = dinv[gw] * (r[gw] + acc) + b3[0];
            float yv = y[gw];
            float L = log1pf(expf(-fabsf(z)));
            float spz  = fmaxf(z, 0.f) + L;    // softplus(z)
            float spnz = fmaxf(-z, 0.f) + L;   // softplus(-z)
            loss = yv * spnz + (1.f - yv) * spz;
        }
    }
    __shared__ float red[4];
    if (lane == 0) red[wave] = loss;
    __syncthreads();
    if (threadIdx.x == 0)
        atomicAdd(out, (red[0] + red[1] + red[2] + red[3]) * invN);
}

// ---------------- launch ----------------
extern "C" void kernel_launch(void* const* d_in, const int* in_sizes, int n_in,
                              void* d_out, int out_size, void* d_ws, size_t ws_size,
                              hipStream_t stream) {
    const float* x  = (const float*)d_in[0];
    const int*   ei = (const int*)d_in[1];
    const float* y  = (const float*)d_in[2];
    const float* W1 = (const float*)d_in[3];
    const float* b1 = (const float*)d_in[4];
    const float* W2 = (const float*)d_in[5];
    const float* b2 = (const float*)d_in[6];
    const float* W3 = (const float*)d_in[7];
    const float* b3 = (const float*)d_in[8];

    const int N = in_sizes[2];        // y has N elements
    const int E = in_sizes[1] / 2;
    const int* src  = ei;
    const int* dstp = ei + E;

    char* w = (char*)d_ws;
    int*    cnt       = (int*)w;    w += (size_t)N * 4;
    int*    cursor    = (int*)w;    w += (size_t)N * 4;
    int*    total     = (int*)w;    w += 16;
    int*    row_start = (int*)w;    w += (size_t)N * 4;
    float*  dinv      = (float*)w;  w += (size_t)N * 4;
    int*    csr       = (int*)w;    w += (size_t)E * 4;
    ushort* wt_hi     = (ushort*)w; w += (size_t)64 * 512 * 2;
    ushort* wt_lo     = (ushort*)w; w += (size_t)64 * 512 * 2;
    ushort* wt2_hi    = (ushort*)w; w += (size_t)256 * 64 * 2;
    ushort* wt2_lo    = (ushort*)w; w += (size_t)256 * 64 * 2;
    ushort* pbuf      = (ushort*)w; w += (size_t)N * 64 * 2;   // p, later a2
    ushort* qbuf      = (ushort*)w; w += (size_t)N * 64 * 2;   // q
    float*  rbuf      = (float*)w;  w += (size_t)N * 4;        // r = dinv*t

    hipMemsetAsync(cnt, 0, (size_t)N * 8 + 16, stream);
    hipMemsetAsync(d_out, 0, sizeof(float), stream);

    const int tb = 256;
    wsplit_kernel<<<(64 * 512 + tb - 1) / tb, tb, 0, stream>>>(W1, wt_hi, wt_lo);
    w2split_kernel<<<(64 * 256 + tb - 1) / tb, tb, 0, stream>>>(W2, wt2_hi, wt2_lo);
    hist_kernel<<<(E + tb - 1) / tb, tb, 0, stream>>>(dstp, E, cnt);
    alloc_kernel<<<(N + tb - 1) / tb, tb, 0, stream>>>(cnt, row_start, dinv, total, N);
    scatter_kernel<<<(E + tb - 1) / tb, tb, 0, stream>>>(src, dstp, E, row_start, cursor, csr);

    // layer 1: p = dinv * (x @ W1) as bf16
    gemm1_kernel<<<(N + 127) / 128, 256, 0, stream>>>(x, wt_hi, wt_lo, dinv, pbuf, N);
    // q = dinv * relu(dinv * (p_self + sum p_nbr) + b1)
    agg64bf_kernel<1, 1, 1><<<(N + 3) / 4, 256, 0, stream>>>(pbuf, qbuf, row_start, cnt, csr, dinv, b1, N);
    // a2 = dinv * (q_self + sum q_nbr)   (reuses pbuf)
    agg64bf_kernel<0, 0, 0><<<(N + 3) / 4, 256, 0, stream>>>(qbuf, pbuf, row_start, cnt, csr, dinv, nullptr, N);

    // layers 2+3 fused via MFMA: r = dinv * (relu(a2 @ W2 + b2) @ W3)
    gemm23_kernel<<<(N + 127) / 128, 256, 0, stream>>>(pbuf, wt2_hi, wt2_lo, b2, W3, dinv, rbuf, N);

    // layer 3 aggregation (wave-per-node, premultiplied) + BCE + mean
    loss_kernel<<<(N * 64 + tb - 1) / tb, tb, 0, stream>>>(rbuf, dinv, row_start, cnt, csr, y, b3,
                                                           (float*)d_out, N, 1.0f / N);
}

// Round 3
// 672.977 us; speedup vs baseline: 1.4365x; 1.4365x over previous
//
#include <hip/hip_runtime.h>
#include <math.h>

typedef __attribute__((ext_vector_type(8))) short s16x8;   // 8 bf16 (4 VGPRs)
typedef __attribute__((ext_vector_type(4))) float f32x4;

__device__ inline ushort f2bf(float f) {
    union { float f; unsigned u; } v; v.f = f;
    unsigned r = v.u + 0x7FFF + ((v.u >> 16) & 1);   // RTN-even
    return (ushort)(r >> 16);
}
__device__ inline float bf2f(ushort h) {
    union { unsigned u; float f; } v; v.u = ((unsigned)h) << 16;
    return v.f;
}
__device__ inline float bfLo(unsigned u) {   // element at even index (low half)
    union { unsigned x; float f; } v; v.x = u << 16; return v.f;
}
__device__ inline float bfHi(unsigned u) {   // element at odd index (high half)
    union { unsigned x; float f; } v; v.x = u & 0xFFFF0000u; return v.f;
}

// ---------------- CSR build ----------------

__global__ void hist_kernel(const int* __restrict__ dst, int E, int* __restrict__ cnt) {
    int e = blockIdx.x * blockDim.x + threadIdx.x;
    if (e < E) atomicAdd(&cnt[dst[e]], 1);
}

__global__ void alloc_kernel(const int* __restrict__ cnt, int* __restrict__ row_start,
                             float* __restrict__ dinv, int* __restrict__ total, int N) {
    int i = blockIdx.x * blockDim.x + threadIdx.x;
    int lane = threadIdx.x & 63;
    int c = (i < N) ? cnt[i] : 0;
    int inc = c;
#pragma unroll
    for (int o = 1; o < 64; o <<= 1) {
        int v = __shfl_up(inc, o, 64);
        if (lane >= o) inc += v;
    }
    int wsum = __shfl(inc, 63, 64);
    int base = 0;
    if (lane == 0) base = atomicAdd(total, wsum);
    base = __shfl(base, 0, 64);
    if (i < N) {
        row_start[i] = base + inc - c;
        dinv[i] = rsqrtf((float)(c + 1));
    }
}

__global__ void scatter_kernel(const int* __restrict__ src, const int* __restrict__ dst, int E,
                               const int* __restrict__ row_start, int* __restrict__ cursor,
                               int* __restrict__ csr) {
    int e = blockIdx.x * blockDim.x + threadIdx.x;
    if (e < E) {
        int d = dst[e];
        int p = row_start[d] + atomicAdd(&cursor[d], 1);
        csr[p] = src[e];
    }
}

// ---------------- W1^T hi/lo split precompute: wt[n][k] bf16 ----------------
__global__ void wsplit_kernel(const float* __restrict__ W, ushort* __restrict__ wt_hi,
                              ushort* __restrict__ wt_lo) {
    int idx = blockIdx.x * blockDim.x + threadIdx.x;
    if (idx < 64 * 512) {
        int n = idx & 63, k = idx >> 6;           // read coalesced over n
        float f = W[k * 64 + n];
        ushort h = f2bf(f);
        wt_hi[n * 512 + k] = h;
        wt_lo[n * 512 + k] = f2bf(f - bf2f(h));
    }
}

// ---------------- W2^T hi/lo split precompute: wt2[n][k] bf16, n=0..255 k=0..63 --------
__global__ void w2split_kernel(const float* __restrict__ W, ushort* __restrict__ wt_hi,
                               ushort* __restrict__ wt_lo) {
    int idx = blockIdx.x * blockDim.x + threadIdx.x;
    if (idx < 64 * 256) {
        int n = idx & 255, k = idx >> 8;          // read coalesced over n
        float f = W[k * 256 + n];
        ushort h = f2bf(f);
        wt_hi[n * 64 + k] = h;
        wt_lo[n * 64 + k] = f2bf(f - bf2f(h));
    }
}

// ---------------- GEMM1 (MFMA): p = dinv * (x @ W1) as bf16, hi/lo 3-term split ----------
__global__ __launch_bounds__(256, 3) void gemm1_kernel(const float* __restrict__ x,
                                                       const ushort* __restrict__ wt_hi,
                                                       const ushort* __restrict__ wt_lo,
                                                       const float* __restrict__ dinv,
                                                       ushort* __restrict__ out, int N) {
    __shared__ __align__(16) short xs_hi[128 * 64];   // 16 KB  [node][g'*8+j]
    __shared__ __align__(16) short xs_lo[128 * 64];   // 16 KB
    __shared__ __align__(16) short ws_hi[64 * 64];    //  8 KB  [n][g'*8+j]
    __shared__ __align__(16) short ws_lo[64 * 64];    //  8 KB

    const int tid = threadIdx.x;
    const int nodeBase = blockIdx.x * 128;
    const int wave = tid >> 6, lane = tid & 63;
    const int m16 = lane & 15, quad = lane >> 4;

    f32x4 acc[2][4];
#pragma unroll
    for (int mt = 0; mt < 2; mt++)
#pragma unroll
        for (int nt = 0; nt < 4; nt++) acc[mt][nt] = (f32x4){0.f, 0.f, 0.f, 0.f};

    for (int kc = 0; kc < 512; kc += 64) {
        __syncthreads();
#pragma unroll
        for (int i = 0; i < 4; i++) {
            int f = tid + i * 256;            // 0..1023
            int node = f >> 3, g = f & 7;
            int gn = nodeBase + node;
            if (gn >= N) gn = N - 1;
            const float4 a = *(const float4*)(x + (size_t)gn * 512 + kc + g * 8);
            const float4 b = *(const float4*)(x + (size_t)gn * 512 + kc + g * 8 + 4);
            float ff[8] = {a.x, a.y, a.z, a.w, b.x, b.y, b.z, b.w};
            union { ushort u[8]; uint4 v; } H, L;
#pragma unroll
            for (int j = 0; j < 8; j++) {
                ushort h = f2bf(ff[j]);
                H.u[j] = h;
                L.u[j] = f2bf(ff[j] - bf2f(h));
            }
            int gp = (g + node) & 7;
            *(uint4*)&xs_hi[node * 64 + gp * 8] = H.v;
            *(uint4*)&xs_lo[node * 64 + gp * 8] = L.v;
        }
#pragma unroll
        for (int i = 0; i < 2; i++) {
            int f = tid + i * 256;            // 0..511
            int n = f >> 3, g = f & 7;
            int gp = (g + n) & 7;
            *(uint4*)&ws_hi[n * 64 + gp * 8] =
                *(const uint4*)(wt_hi + (size_t)n * 512 + kc + g * 8);
            *(uint4*)&ws_lo[n * 64 + gp * 8] =
                *(const uint4*)(wt_lo + (size_t)n * 512 + kc + g * 8);
        }
        __syncthreads();
#pragma unroll
        for (int ck = 0; ck < 2; ck++) {
            s16x8 Ah[2], Al[2];
#pragma unroll
            for (int mt = 0; mt < 2; mt++) {
                int row = (wave * 2 + mt) * 16 + m16;     // local 0..127
                int gp = (ck * 4 + quad + row) & 7;
                Ah[mt] = *(s16x8*)&xs_hi[row * 64 + gp * 8];
                Al[mt] = *(s16x8*)&xs_lo[row * 64 + gp * 8];
            }
#pragma unroll
            for (int nt = 0; nt < 4; nt++) {
                int n = nt * 16 + m16;                    // local 0..63
                int gp = (ck * 4 + quad + n) & 7;
                s16x8 Bh = *(s16x8*)&ws_hi[n * 64 + gp * 8];
                s16x8 Bl = *(s16x8*)&ws_lo[n * 64 + gp * 8];
#pragma unroll
                for (int mt = 0; mt < 2; mt++) {
                    acc[mt][nt] = __builtin_amdgcn_mfma_f32_16x16x32_bf16(Ah[mt], Bh, acc[mt][nt], 0, 0, 0);
                    acc[mt][nt] = __builtin_amdgcn_mfma_f32_16x16x32_bf16(Ah[mt], Bl, acc[mt][nt], 0, 0, 0);
                    acc[mt][nt] = __builtin_amdgcn_mfma_f32_16x16x32_bf16(Al[mt], Bh, acc[mt][nt], 0, 0, 0);
                }
            }
        }
    }
    // C/D layout: col = lane&15, row = quad*4 + reg. Write p = dinv*acc as bf16.
#pragma unroll
    for (int mt = 0; mt < 2; mt++) {
#pragma unroll
        for (int r = 0; r < 4; r++) {
            int gn = nodeBase + (wave * 2 + mt) * 16 + quad * 4 + r;
            if (gn < N) {
                float di = dinv[gn];
#pragma unroll
                for (int nt = 0; nt < 4; nt++)
                    out[(size_t)gn * 64 + nt * 16 + m16] = f2bf(di * acc[mt][nt][r]);
            }
        }
    }
}

// ---------------- 64-dim CSR aggregation, vectorized: 4 rows per wave-instruction -------
// out[i] = post( dinv[i] * (in[i] + sum_j in[j]) ), one wave per node.
// Lane layout: quad = lane>>4 handles neighbor slot e+quad; 16 lanes cover the full
// 128 B row with uint2 (4 bf16 each). Slot 0 = self loop. Two batches in flight.
template <int RELU, int BIAS, int PREMUL>
__global__ void agg64bf_kernel(const ushort* __restrict__ in, ushort* __restrict__ out,
                               const int* __restrict__ row_start, const int* __restrict__ cnt,
                               const int* __restrict__ csr, const float* __restrict__ dinv,
                               const float* __restrict__ bias, int N) {
    int gw = (int)((blockIdx.x * (size_t)blockDim.x + threadIdx.x) >> 6);
    int lane = threadIdx.x & 63;
    if (gw >= N) return;
    const int m16 = lane & 15;        // feature group: features 4*m16 .. 4*m16+3
    const int quad = lane >> 4;       // neighbor slot within the batch of 4

    const int s = row_start[gw];
    const int c = cnt[gw];
    const int total = c + 1;          // slot 0 = self, slots 1..c = neighbors

    float a0 = 0.f, a1 = 0.f, a2v = 0.f, a3 = 0.f;
    for (int e = 0; e < total; e += 8) {
        int s0 = e + quad, s1 = e + 4 + quad;
        bool v0 = s0 < total, v1 = s1 < total;
        int j0 = gw, j1 = gw;
        if (v0 && s0 > 0) j0 = csr[s + s0 - 1];
        if (v1 && s1 > 0) j1 = csr[s + s1 - 1];
        uint2 u0 = *(const uint2*)(in + (size_t)j0 * 64 + m16 * 4);
        uint2 u1 = *(const uint2*)(in + (size_t)j1 * 64 + m16 * 4);
        if (v0) { a0 += bfLo(u0.x); a1 += bfHi(u0.x); a2v += bfLo(u0.y); a3 += bfHi(u0.y); }
        if (v1) { a0 += bfLo(u1.x); a1 += bfHi(u1.x); a2v += bfLo(u1.y); a3 += bfHi(u1.y); }
    }
    // combine the 4 quads (lane ^16, ^32)
    a0 += __shfl_xor(a0, 16, 64); a0 += __shfl_xor(a0, 32, 64);
    a1 += __shfl_xor(a1, 16, 64); a1 += __shfl_xor(a1, 32, 64);
    a2v += __shfl_xor(a2v, 16, 64); a2v += __shfl_xor(a2v, 32, 64);
    a3 += __shfl_xor(a3, 16, 64); a3 += __shfl_xor(a3, 32, 64);

    float di = dinv[gw];
    float r0 = di * a0, r1 = di * a1, r2 = di * a2v, r3 = di * a3;
    if (BIAS) {
        float4 bv = *(const float4*)&bias[m16 * 4];
        r0 += bv.x; r1 += bv.y; r2 += bv.z; r3 += bv.w;
    }
    if (RELU) {
        r0 = fmaxf(r0, 0.f); r1 = fmaxf(r1, 0.f);
        r2 = fmaxf(r2, 0.f); r3 = fmaxf(r3, 0.f);
    }
    if (PREMUL) { r0 *= di; r1 *= di; r2 *= di; r3 *= di; }
    if (quad == 0) {
        uint2 o;
        o.x = ((unsigned)f2bf(r1) << 16) | f2bf(r0);
        o.y = ((unsigned)f2bf(r3) << 16) | f2bf(r2);
        *(uint2*)(out + (size_t)gw * 64 + m16 * 4) = o;
    }
}

// ---------------- fused GEMM2 (+bias,relu) + GEMM3, MFMA version ----------------
// r[i] = dinv[i] * (relu(a2[i] @ W2 + b2) @ W3)
// a2 is ALREADY bf16 (exact A operand). W2 split into bf16 hi/lo (2-term).
// Fragments loaded directly from global; no LDS, no barriers. W2^T hi/lo L2-resident.
__global__ __launch_bounds__(256, 2) void gemm23_kernel(const ushort* __restrict__ a2,
                                                        const ushort* __restrict__ wt2_hi,
                                                        const ushort* __restrict__ wt2_lo,
                                                        const float* __restrict__ b2,
                                                        const float* __restrict__ W3,
                                                        const float* __restrict__ dinv,
                                                        float* __restrict__ r, int N) {
    const int tid = threadIdx.x;
    const int wave = tid >> 6, lane = tid & 63;
    const int m16 = lane & 15, quad = lane >> 4;
    const int rowBase = blockIdx.x * 128 + wave * 32;   // wave covers 32 nodes

    // A fragments: row = rowBase + mt*16 + m16, k = ck*32 + quad*8 .. +8
    s16x8 A[2][2];
#pragma unroll
    for (int mt = 0; mt < 2; mt++) {
        int gn = rowBase + mt * 16 + m16;
        if (gn >= N) gn = N - 1;
        const ushort* ap = a2 + (size_t)gn * 64 + quad * 8;
#pragma unroll
        for (int ck = 0; ck < 2; ck++)
            A[mt][ck] = *(const s16x8*)(ap + ck * 32);
    }

    f32x4 acc[2][16];
#pragma unroll
    for (int mt = 0; mt < 2; mt++)
#pragma unroll
        for (int nt = 0; nt < 16; nt++) acc[mt][nt] = (f32x4){0.f, 0.f, 0.f, 0.f};

#pragma unroll
    for (int nt = 0; nt < 16; nt++) {
        int n = nt * 16 + m16;                           // output col 0..255
        const ushort* bh = wt2_hi + (size_t)n * 64 + quad * 8;
        const ushort* bl = wt2_lo + (size_t)n * 64 + quad * 8;
        s16x8 Bh0 = *(const s16x8*)(bh);
        s16x8 Bh1 = *(const s16x8*)(bh + 32);
        s16x8 Bl0 = *(const s16x8*)(bl);
        s16x8 Bl1 = *(const s16x8*)(bl + 32);
        acc[0][nt] = __builtin_amdgcn_mfma_f32_16x16x32_bf16(A[0][0], Bh0, acc[0][nt], 0, 0, 0);
        acc[1][nt] = __builtin_amdgcn_mfma_f32_16x16x32_bf16(A[1][0], Bh0, acc[1][nt], 0, 0, 0);
        acc[0][nt] = __builtin_amdgcn_mfma_f32_16x16x32_bf16(A[0][1], Bh1, acc[0][nt], 0, 0, 0);
        acc[1][nt] = __builtin_amdgcn_mfma_f32_16x16x32_bf16(A[1][1], Bh1, acc[1][nt], 0, 0, 0);
        acc[0][nt] = __builtin_amdgcn_mfma_f32_16x16x32_bf16(A[0][0], Bl0, acc[0][nt], 0, 0, 0);
        acc[1][nt] = __builtin_amdgcn_mfma_f32_16x16x32_bf16(A[1][0], Bl0, acc[1][nt], 0, 0, 0);
        acc[0][nt] = __builtin_amdgcn_mfma_f32_16x16x32_bf16(A[0][1], Bl1, acc[0][nt], 0, 0, 0);
        acc[1][nt] = __builtin_amdgcn_mfma_f32_16x16x32_bf16(A[1][1], Bl1, acc[1][nt], 0, 0, 0);
    }

    // epilogue: per lane holds cols {nt*16+m16} of rows {mt*16+quad*4+rr}
    float bv[16], wv[16];
#pragma unroll
    for (int nt = 0; nt < 16; nt++) {
        bv[nt] = b2[nt * 16 + m16];
        wv[nt] = W3[nt * 16 + m16];
    }
#pragma unroll
    for (int mt = 0; mt < 2; mt++) {
#pragma unroll
        for (int rr = 0; rr < 4; rr++) {
            float p = 0.f;
#pragma unroll
            for (int nt = 0; nt < 16; nt++) {
                float v = fmaxf(acc[mt][nt][rr] + bv[nt], 0.f);
                p = fmaf(v, wv[nt], p);
            }
            // reduce the 16-lane m16 group (same quad = same row)
#pragma unroll
            for (int off = 1; off < 16; off <<= 1) p += __shfl_xor(p, off, 64);
            int gn = rowBase + mt * 16 + quad * 4 + rr;
            if (m16 == 0 && gn < N) r[gn] = dinv[gn] * p;
        }
    }
}

// ---------------- loss: 16-lane-group-per-node gather + BCE, few atomics ----------------
// Grid-stride over nodes; 4 nodes per wave; block-level LDS reduce -> 1 atomic/block.
__global__ __launch_bounds__(1024) void loss_kernel(const float* __restrict__ r,
                                                    const float* __restrict__ dinv,
                                                    const int* __restrict__ row_start,
                                                    const int* __restrict__ cnt,
                                                    const int* __restrict__ csr,
                                                    const float* __restrict__ y,
                                                    const float* __restrict__ b3,
                                                    float* __restrict__ out,
                                                    int N, float invN) {
    const int lane = threadIdx.x & 63;
    const int wave = threadIdx.x >> 6;       // 0..15
    const int l16 = lane & 15;
    const int grp = lane >> 4;               // 0..3: node slot within wave
    const int waveId = blockIdx.x * 16 + wave;
    const int nWaves = gridDim.x * 16;
    const float b3v = b3[0];

    float loss = 0.f;
    for (int base = waveId * 4; base < N; base += nWaves * 4) {
        int node = base + grp;
        float acc = 0.f;
        if (node < N) {
            int s = row_start[node], c = cnt[node];
            for (int e = l16; e < c; e += 16) acc += r[csr[s + e]];
        }
        // reduce within the 16-lane group
        acc += __shfl_xor(acc, 1, 64);
        acc += __shfl_xor(acc, 2, 64);
        acc += __shfl_xor(acc, 4, 64);
        acc += __shfl_xor(acc, 8, 64);
        if (node < N && l16 == 0) {
            float z = dinv[node] * (r[node] + acc) + b3v;
            float yv = y[node];
            float L = log1pf(expf(-fabsf(z)));
            float spz  = fmaxf(z, 0.f) + L;    // softplus(z)
            float spnz = fmaxf(-z, 0.f) + L;   // softplus(-z)
            loss += yv * spnz + (1.f - yv) * spz;
        }
    }
#pragma unroll
    for (int off = 1; off < 64; off <<= 1) loss += __shfl_xor(loss, off, 64);
    __shared__ float red[16];
    if (lane == 0) red[wave] = loss;
    __syncthreads();
    if (threadIdx.x == 0) {
        float t = 0.f;
#pragma unroll
        for (int i = 0; i < 16; i++) t += red[i];
        atomicAdd(out, t * invN);
    }
}

// ---------------- launch ----------------
extern "C" void kernel_launch(void* const* d_in, const int* in_sizes, int n_in,
                              void* d_out, int out_size, void* d_ws, size_t ws_size,
                              hipStream_t stream) {
    const float* x  = (const float*)d_in[0];
    const int*   ei = (const int*)d_in[1];
    const float* y  = (const float*)d_in[2];
    const float* W1 = (const float*)d_in[3];
    const float* b1 = (const float*)d_in[4];
    const float* W2 = (const float*)d_in[5];
    const float* b2 = (const float*)d_in[6];
    const float* W3 = (const float*)d_in[7];
    const float* b3 = (const float*)d_in[8];

    const int N = in_sizes[2];        // y has N elements
    const int E = in_sizes[1] / 2;
    const int* src  = ei;
    const int* dstp = ei + E;

    char* w = (char*)d_ws;
    int*    cnt       = (int*)w;    w += (size_t)N * 4;
    int*    cursor    = (int*)w;    w += (size_t)N * 4;
    int*    total     = (int*)w;    w += 16;
    int*    row_start = (int*)w;    w += (size_t)N * 4;
    float*  dinv      = (float*)w;  w += (size_t)N * 4;
    int*    csr       = (int*)w;    w += (size_t)E * 4;
    ushort* wt_hi     = (ushort*)w; w += (size_t)64 * 512 * 2;
    ushort* wt_lo     = (ushort*)w; w += (size_t)64 * 512 * 2;
    ushort* wt2_hi    = (ushort*)w; w += (size_t)256 * 64 * 2;
    ushort* wt2_lo    = (ushort*)w; w += (size_t)256 * 64 * 2;
    ushort* pbuf      = (ushort*)w; w += (size_t)N * 64 * 2;   // p, later a2
    ushort* qbuf      = (ushort*)w; w += (size_t)N * 64 * 2;   // q
    float*  rbuf      = (float*)w;  w += (size_t)N * 4;        // r = dinv*t

    hipMemsetAsync(cnt, 0, (size_t)N * 8 + 16, stream);
    hipMemsetAsync(d_out, 0, sizeof(float), stream);

    const int tb = 256;
    wsplit_kernel<<<(64 * 512 + tb - 1) / tb, tb, 0, stream>>>(W1, wt_hi, wt_lo);
    w2split_kernel<<<(64 * 256 + tb - 1) / tb, tb, 0, stream>>>(W2, wt2_hi, wt2_lo);
    hist_kernel<<<(E + tb - 1) / tb, tb, 0, stream>>>(dstp, E, cnt);
    alloc_kernel<<<(N + tb - 1) / tb, tb, 0, stream>>>(cnt, row_start, dinv, total, N);
    scatter_kernel<<<(E + tb - 1) / tb, tb, 0, stream>>>(src, dstp, E, row_start, cursor, csr);

    // layer 1: p = dinv * (x @ W1) as bf16
    gemm1_kernel<<<(N + 127) / 128, 256, 0, stream>>>(x, wt_hi, wt_lo, dinv, pbuf, N);
    // q = dinv * relu(dinv * (p_self + sum p_nbr) + b1)
    agg64bf_kernel<1, 1, 1><<<(N + 3) / 4, 256, 0, stream>>>(pbuf, qbuf, row_start, cnt, csr, dinv, b1, N);
    // a2 = dinv * (q_self + sum q_nbr)   (reuses pbuf)
    agg64bf_kernel<0, 0, 0><<<(N + 3) / 4, 256, 0, stream>>>(qbuf, pbuf, row_start, cnt, csr, dinv, nullptr, N);

    // layers 2+3 fused via MFMA: r = dinv * (relu(a2 @ W2 + b2) @ W3)
    gemm23_kernel<<<(N + 127) / 128, 256, 0, stream>>>(pbuf, wt2_hi, wt2_lo, b2, W3, dinv, rbuf, N);

    // layer 3 aggregation (16-lane groups, grid-stride, 256 atomics) + BCE + mean
    loss_kernel<<<256, 1024, 0, stream>>>(rbuf, dinv, row_start, cnt, csr, y, b3,
                                          (float*)d_out, N, 1.0f / N);
}

// Round 4
// 627.108 us; speedup vs baseline: 1.5416x; 1.0731x over previous
//
#include <hip/hip_runtime.h>
#include <math.h>

typedef __attribute__((ext_vector_type(8))) short s16x8;   // 8 bf16 (4 VGPRs)
typedef __attribute__((ext_vector_type(4))) float f32x4;

__device__ inline ushort f2bf(float f) {
    union { float f; unsigned u; } v; v.f = f;
    unsigned r = v.u + 0x7FFF + ((v.u >> 16) & 1);   // RTN-even
    return (ushort)(r >> 16);
}
__device__ inline float bf2f(ushort h) {
    union { unsigned u; float f; } v; v.u = ((unsigned)h) << 16;
    return v.f;
}
__device__ inline float bfLo(unsigned u) {   // element at even index (low half)
    union { unsigned x; float f; } v; v.x = u << 16; return v.f;
}
__device__ inline float bfHi(unsigned u) {   // element at odd index (high half)
    union { unsigned x; float f; } v; v.x = u & 0xFFFF0000u; return v.f;
}

// ---------------- CSR build ----------------
// hist uses the atomic return value as the edge's slot within its row; scatter is
// then atomic-free (1.6M fewer contended RMWs than the cursor scheme).

__global__ void hist_kernel(const int* __restrict__ dst, int E, int* __restrict__ cnt,
                            int* __restrict__ slot) {
    int e = blockIdx.x * blockDim.x + threadIdx.x;
    if (e < E) slot[e] = atomicAdd(&cnt[dst[e]], 1);
}

__global__ void alloc_kernel(const int* __restrict__ cnt, int* __restrict__ row_start,
                             float* __restrict__ dinv, int* __restrict__ total, int N) {
    int i = blockIdx.x * blockDim.x + threadIdx.x;
    int lane = threadIdx.x & 63;
    int c = (i < N) ? cnt[i] : 0;
    int inc = c;
#pragma unroll
    for (int o = 1; o < 64; o <<= 1) {
        int v = __shfl_up(inc, o, 64);
        if (lane >= o) inc += v;
    }
    int wsum = __shfl(inc, 63, 64);
    int base = 0;
    if (lane == 0) base = atomicAdd(total, wsum);
    base = __shfl(base, 0, 64);
    if (i < N) {
        row_start[i] = base + inc - c;
        dinv[i] = rsqrtf((float)(c + 1));
    }
}

__global__ void scatter_kernel(const int* __restrict__ src, const int* __restrict__ dst, int E,
                               const int* __restrict__ row_start, const int* __restrict__ slot,
                               int* __restrict__ csr) {
    int e = blockIdx.x * blockDim.x + threadIdx.x;
    if (e < E) {
        int d = dst[e];
        csr[row_start[d] + slot[e]] = src[e];
    }
}

// ---------------- W1^T and W2^T hi/lo split precompute (one launch) ----------------
// wt[n][k] bf16 (n=0..63, k=0..511); wt2[n][k] bf16 (n=0..255, k=0..63)
__global__ void wsplit_all_kernel(const float* __restrict__ W1, const float* __restrict__ W2,
                                  ushort* __restrict__ wt_hi, ushort* __restrict__ wt_lo,
                                  ushort* __restrict__ wt2_hi, ushort* __restrict__ wt2_lo) {
    int idx = blockIdx.x * blockDim.x + threadIdx.x;
    if (idx < 64 * 512) {
        int n = idx & 63, k = idx >> 6;           // read coalesced over n
        float f = W1[k * 64 + n];
        ushort h = f2bf(f);
        wt_hi[n * 512 + k] = h;
        wt_lo[n * 512 + k] = f2bf(f - bf2f(h));
    } else if (idx < 64 * 512 + 64 * 256) {
        int i2 = idx - 64 * 512;
        int n = i2 & 255, k = i2 >> 8;            // read coalesced over n
        float f = W2[k * 256 + n];
        ushort h = f2bf(f);
        wt2_hi[n * 64 + k] = h;
        wt2_lo[n * 64 + k] = f2bf(f - bf2f(h));
    }
}

// ---------------- GEMM1 (MFMA): p = dinv * (x @ W1) as bf16, hi/lo 3-term split ----------
__global__ __launch_bounds__(256, 3) void gemm1_kernel(const float* __restrict__ x,
                                                       const ushort* __restrict__ wt_hi,
                                                       const ushort* __restrict__ wt_lo,
                                                       const float* __restrict__ dinv,
                                                       ushort* __restrict__ out, int N) {
    __shared__ __align__(16) short xs_hi[128 * 64];   // 16 KB  [node][g'*8+j]
    __shared__ __align__(16) short xs_lo[128 * 64];   // 16 KB
    __shared__ __align__(16) short ws_hi[64 * 64];    //  8 KB  [n][g'*8+j]
    __shared__ __align__(16) short ws_lo[64 * 64];    //  8 KB

    const int tid = threadIdx.x;
    const int nodeBase = blockIdx.x * 128;
    const int wave = tid >> 6, lane = tid & 63;
    const int m16 = lane & 15, quad = lane >> 4;

    f32x4 acc[2][4];
#pragma unroll
    for (int mt = 0; mt < 2; mt++)
#pragma unroll
        for (int nt = 0; nt < 4; nt++) acc[mt][nt] = (f32x4){0.f, 0.f, 0.f, 0.f};

    for (int kc = 0; kc < 512; kc += 64) {
        __syncthreads();
#pragma unroll
        for (int i = 0; i < 4; i++) {
            int f = tid + i * 256;            // 0..1023
            int node = f >> 3, g = f & 7;
            int gn = nodeBase + node;
            if (gn >= N) gn = N - 1;
            const float4 a = *(const float4*)(x + (size_t)gn * 512 + kc + g * 8);
            const float4 b = *(const float4*)(x + (size_t)gn * 512 + kc + g * 8 + 4);
            float ff[8] = {a.x, a.y, a.z, a.w, b.x, b.y, b.z, b.w};
            union { ushort u[8]; uint4 v; } H, L;
#pragma unroll
            for (int j = 0; j < 8; j++) {
                ushort h = f2bf(ff[j]);
                H.u[j] = h;
                L.u[j] = f2bf(ff[j] - bf2f(h));
            }
            int gp = (g + node) & 7;
            *(uint4*)&xs_hi[node * 64 + gp * 8] = H.v;
            *(uint4*)&xs_lo[node * 64 + gp * 8] = L.v;
        }
#pragma unroll
        for (int i = 0; i < 2; i++) {
            int f = tid + i * 256;            // 0..511
            int n = f >> 3, g = f & 7;
            int gp = (g + n) & 7;
            *(uint4*)&ws_hi[n * 64 + gp * 8] =
                *(const uint4*)(wt_hi + (size_t)n * 512 + kc + g * 8);
            *(uint4*)&ws_lo[n * 64 + gp * 8] =
                *(const uint4*)(wt_lo + (size_t)n * 512 + kc + g * 8);
        }
        __syncthreads();
#pragma unroll
        for (int ck = 0; ck < 2; ck++) {
            s16x8 Ah[2], Al[2];
#pragma unroll
            for (int mt = 0; mt < 2; mt++) {
                int row = (wave * 2 + mt) * 16 + m16;     // local 0..127
                int gp = (ck * 4 + quad + row) & 7;
                Ah[mt] = *(s16x8*)&xs_hi[row * 64 + gp * 8];
                Al[mt] = *(s16x8*)&xs_lo[row * 64 + gp * 8];
            }
#pragma unroll
            for (int nt = 0; nt < 4; nt++) {
                int n = nt * 16 + m16;                    // local 0..63
                int gp = (ck * 4 + quad + n) & 7;
                s16x8 Bh = *(s16x8*)&ws_hi[n * 64 + gp * 8];
                s16x8 Bl = *(s16x8*)&ws_lo[n * 64 + gp * 8];
#pragma unroll
                for (int mt = 0; mt < 2; mt++) {
                    acc[mt][nt] = __builtin_amdgcn_mfma_f32_16x16x32_bf16(Ah[mt], Bh, acc[mt][nt], 0, 0, 0);
                    acc[mt][nt] = __builtin_amdgcn_mfma_f32_16x16x32_bf16(Ah[mt], Bl, acc[mt][nt], 0, 0, 0);
                    acc[mt][nt] = __builtin_amdgcn_mfma_f32_16x16x32_bf16(Al[mt], Bh, acc[mt][nt], 0, 0, 0);
                }
            }
        }
    }
    // C/D layout: col = lane&15, row = quad*4 + reg. Write p = dinv*acc as bf16.
#pragma unroll
    for (int mt = 0; mt < 2; mt++) {
#pragma unroll
        for (int r = 0; r < 4; r++) {
            int gn = nodeBase + (wave * 2 + mt) * 16 + quad * 4 + r;
            if (gn < N) {
                float di = dinv[gn];
#pragma unroll
                for (int nt = 0; nt < 4; nt++)
                    out[(size_t)gn * 64 + nt * 16 + m16] = f2bf(di * acc[mt][nt][r]);
            }
        }
    }
}

// ---------------- 64-dim CSR aggregation, vectorized: 4 rows per wave-instruction -------
// out[i] = post( dinv[i] * (in[i] + sum_j in[j]) ), one wave per node.
// Lane layout: quad = lane>>4 handles neighbor slot e+quad; 16 lanes cover the full
// 128 B row with uint2 (4 bf16 each). Slot 0 = self loop. Two batches in flight.
template <int RELU, int BIAS, int PREMUL>
__global__ void agg64bf_kernel(const ushort* __restrict__ in, ushort* __restrict__ out,
                               const int* __restrict__ row_start, const int* __restrict__ cnt,
                               const int* __restrict__ csr, const float* __restrict__ dinv,
                               const float* __restrict__ bias, int N) {
    int gw = (int)((blockIdx.x * (size_t)blockDim.x + threadIdx.x) >> 6);
    int lane = threadIdx.x & 63;
    if (gw >= N) return;
    const int m16 = lane & 15;        // feature group: features 4*m16 .. 4*m16+3
    const int quad = lane >> 4;       // neighbor slot within the batch of 4

    const int s = row_start[gw];
    const int c = cnt[gw];
    const int total = c + 1;          // slot 0 = self, slots 1..c = neighbors

    float a0 = 0.f, a1 = 0.f, a2v = 0.f, a3 = 0.f;
    for (int e = 0; e < total; e += 8) {
        int s0 = e + quad, s1 = e + 4 + quad;
        bool v0 = s0 < total, v1 = s1 < total;
        int j0 = gw, j1 = gw;
        if (v0 && s0 > 0) j0 = csr[s + s0 - 1];
        if (v1 && s1 > 0) j1 = csr[s + s1 - 1];
        uint2 u0 = *(const uint2*)(in + (size_t)j0 * 64 + m16 * 4);
        uint2 u1 = *(const uint2*)(in + (size_t)j1 * 64 + m16 * 4);
        if (v0) { a0 += bfLo(u0.x); a1 += bfHi(u0.x); a2v += bfLo(u0.y); a3 += bfHi(u0.y); }
        if (v1) { a0 += bfLo(u1.x); a1 += bfHi(u1.x); a2v += bfLo(u1.y); a3 += bfHi(u1.y); }
    }
    // combine the 4 quads (lane ^16, ^32)
    a0 += __shfl_xor(a0, 16, 64); a0 += __shfl_xor(a0, 32, 64);
    a1 += __shfl_xor(a1, 16, 64); a1 += __shfl_xor(a1, 32, 64);
    a2v += __shfl_xor(a2v, 16, 64); a2v += __shfl_xor(a2v, 32, 64);
    a3 += __shfl_xor(a3, 16, 64); a3 += __shfl_xor(a3, 32, 64);

    float di = dinv[gw];
    float r0 = di * a0, r1 = di * a1, r2 = di * a2v, r3 = di * a3;
    if (BIAS) {
        float4 bv = *(const float4*)&bias[m16 * 4];
        r0 += bv.x; r1 += bv.y; r2 += bv.z; r3 += bv.w;
    }
    if (RELU) {
        r0 = fmaxf(r0, 0.f); r1 = fmaxf(r1, 0.f);
        r2 = fmaxf(r2, 0.f); r3 = fmaxf(r3, 0.f);
    }
    if (PREMUL) { r0 *= di; r1 *= di; r2 *= di; r3 *= di; }
    if (quad == 0) {
        uint2 o;
        o.x = ((unsigned)f2bf(r1) << 16) | f2bf(r0);
        o.y = ((unsigned)f2bf(r3) << 16) | f2bf(r2);
        *(uint2*)(out + (size_t)gw * 64 + m16 * 4) = o;
    }
}

// ---------------- fused GEMM2 (+bias,relu) + GEMM3, MFMA version ----------------
// r[i] = dinv[i] * (relu(a2[i] @ W2 + b2) @ W3)
// a2 is ALREADY bf16 (exact A operand). W2 split into bf16 hi/lo (2-term).
// Fragments loaded directly from global; no LDS, no barriers. W2^T hi/lo L2-resident.
__global__ __launch_bounds__(256, 2) void gemm23_kernel(const ushort* __restrict__ a2,
                                                        const ushort* __restrict__ wt2_hi,
                                                        const ushort* __restrict__ wt2_lo,
                                                        const float* __restrict__ b2,
                                                        const float* __restrict__ W3,
                                                        const float* __restrict__ dinv,
                                                        float* __restrict__ r, int N) {
    const int tid = threadIdx.x;
    const int wave = tid >> 6, lane = tid & 63;
    const int m16 = lane & 15, quad = lane >> 4;
    const int rowBase = blockIdx.x * 128 + wave * 32;   // wave covers 32 nodes

    // A fragments: row = rowBase + mt*16 + m16, k = ck*32 + quad*8 .. +8
    s16x8 A[2][2];
#pragma unroll
    for (int mt = 0; mt < 2; mt++) {
        int gn = rowBase + mt * 16 + m16;
        if (gn >= N) gn = N - 1;
        const ushort* ap = a2 + (size_t)gn * 64 + quad * 8;
#pragma unroll
        for (int ck = 0; ck < 2; ck++)
            A[mt][ck] = *(const s16x8*)(ap + ck * 32);
    }

    f32x4 acc[2][16];
#pragma unroll
    for (int mt = 0; mt < 2; mt++)
#pragma unroll
        for (int nt = 0; nt < 16; nt++) acc[mt][nt] = (f32x4){0.f, 0.f, 0.f, 0.f};

#pragma unroll
    for (int nt = 0; nt < 16; nt++) {
        int n = nt * 16 + m16;                           // output col 0..255
        const ushort* bh = wt2_hi + (size_t)n * 64 + quad * 8;
        const ushort* bl = wt2_lo + (size_t)n * 64 + quad * 8;
        s16x8 Bh0 = *(const s16x8*)(bh);
        s16x8 Bh1 = *(const s16x8*)(bh + 32);
        s16x8 Bl0 = *(const s16x8*)(bl);
        s16x8 Bl1 = *(const s16x8*)(bl + 32);
        acc[0][nt] = __builtin_amdgcn_mfma_f32_16x16x32_bf16(A[0][0], Bh0, acc[0][nt], 0, 0, 0);
        acc[1][nt] = __builtin_amdgcn_mfma_f32_16x16x32_bf16(A[1][0], Bh0, acc[1][nt], 0, 0, 0);
        acc[0][nt] = __builtin_amdgcn_mfma_f32_16x16x32_bf16(A[0][1], Bh1, acc[0][nt], 0, 0, 0);
        acc[1][nt] = __builtin_amdgcn_mfma_f32_16x16x32_bf16(A[1][1], Bh1, acc[1][nt], 0, 0, 0);
        acc[0][nt] = __builtin_amdgcn_mfma_f32_16x16x32_bf16(A[0][0], Bl0, acc[0][nt], 0, 0, 0);
        acc[1][nt] = __builtin_amdgcn_mfma_f32_16x16x32_bf16(A[1][0], Bl0, acc[1][nt], 0, 0, 0);
        acc[0][nt] = __builtin_amdgcn_mfma_f32_16x16x32_bf16(A[0][1], Bl1, acc[0][nt], 0, 0, 0);
        acc[1][nt] = __builtin_amdgcn_mfma_f32_16x16x32_bf16(A[1][1], Bl1, acc[1][nt], 0, 0, 0);
    }

    // epilogue: per lane holds cols {nt*16+m16} of rows {mt*16+quad*4+rr}
    float bv[16], wv[16];
#pragma unroll
    for (int nt = 0; nt < 16; nt++) {
        bv[nt] = b2[nt * 16 + m16];
        wv[nt] = W3[nt * 16 + m16];
    }
#pragma unroll
    for (int mt = 0; mt < 2; mt++) {
#pragma unroll
        for (int rr = 0; rr < 4; rr++) {
            float p = 0.f;
#pragma unroll
            for (int nt = 0; nt < 16; nt++) {
                float v = fmaxf(acc[mt][nt][rr] + bv[nt], 0.f);
                p = fmaf(v, wv[nt], p);
            }
            // reduce the 16-lane m16 group (same quad = same row)
#pragma unroll
            for (int off = 1; off < 16; off <<= 1) p += __shfl_xor(p, off, 64);
            int gn = rowBase + mt * 16 + quad * 4 + rr;
            if (m16 == 0 && gn < N) r[gn] = dinv[gn] * p;
        }
    }
}

// ---------------- loss: 16-lane-group-per-node gather + BCE, few atomics ----------------
// Grid-stride over nodes; 4 nodes per wave; block-level LDS reduce -> 1 atomic/block.
__global__ __launch_bounds__(1024) void loss_kernel(const float* __restrict__ r,
                                                    const float* __restrict__ dinv,
                                                    const int* __restrict__ row_start,
                                                    const int* __restrict__ cnt,
                                                    const int* __restrict__ csr,
                                                    const float* __restrict__ y,
                                                    const float* __restrict__ b3,
                                                    float* __restrict__ out,
                                                    int N, float invN) {
    const int lane = threadIdx.x & 63;
    const int wave = threadIdx.x >> 6;       // 0..15
    const int l16 = lane & 15;
    const int grp = lane >> 4;               // 0..3: node slot within wave
    const int waveId = blockIdx.x * 16 + wave;
    const int nWaves = gridDim.x * 16;
    const float b3v = b3[0];

    float loss = 0.f;
    for (int base = waveId * 4; base < N; base += nWaves * 4) {
        int node = base + grp;
        float acc = 0.f;
        if (node < N) {
            int s = row_start[node], c = cnt[node];
            for (int e = l16; e < c; e += 16) acc += r[csr[s + e]];
        }
        // reduce within the 16-lane group
        acc += __shfl_xor(acc, 1, 64);
        acc += __shfl_xor(acc, 2, 64);
        acc += __shfl_xor(acc, 4, 64);
        acc += __shfl_xor(acc, 8, 64);
        if (node < N && l16 == 0) {
            float z = dinv[node] * (r[node] + acc) + b3v;
            float yv = y[node];
            float L = log1pf(expf(-fabsf(z)));
            float spz  = fmaxf(z, 0.f) + L;    // softplus(z)
            float spnz = fmaxf(-z, 0.f) + L;   // softplus(-z)
            loss += yv * spnz + (1.f - yv) * spz;
        }
    }
#pragma unroll
    for (int off = 1; off < 64; off <<= 1) loss += __shfl_xor(loss, off, 64);
    __shared__ float red[16];
    if (lane == 0) red[wave] = loss;
    __syncthreads();
    if (threadIdx.x == 0) {
        float t = 0.f;
#pragma unroll
        for (int i = 0; i < 16; i++) t += red[i];
        atomicAdd(out, t * invN);
    }
}

// ---------------- launch ----------------
extern "C" void kernel_launch(void* const* d_in, const int* in_sizes, int n_in,
                              void* d_out, int out_size, void* d_ws, size_t ws_size,
                              hipStream_t stream) {
    const float* x  = (const float*)d_in[0];
    const int*   ei = (const int*)d_in[1];
    const float* y  = (const float*)d_in[2];
    const float* W1 = (const float*)d_in[3];
    const float* b1 = (const float*)d_in[4];
    const float* W2 = (const float*)d_in[5];
    const float* b2 = (const float*)d_in[6];
    const float* W3 = (const float*)d_in[7];
    const float* b3 = (const float*)d_in[8];

    const int N = in_sizes[2];        // y has N elements
    const int E = in_sizes[1] / 2;
    const int* src  = ei;
    const int* dstp = ei + E;

    char* w = (char*)d_ws;
    int*    cnt       = (int*)w;    w += (size_t)N * 4;
    int*    total     = (int*)w;    w += 16;
    int*    row_start = (int*)w;    w += (size_t)N * 4;
    float*  dinv      = (float*)w;  w += (size_t)N * 4;
    int*    csr       = (int*)w;    w += (size_t)E * 4;
    int*    slot      = (int*)w;    w += (size_t)E * 4;
    ushort* wt_hi     = (ushort*)w; w += (size_t)64 * 512 * 2;
    ushort* wt_lo     = (ushort*)w; w += (size_t)64 * 512 * 2;
    ushort* wt2_hi    = (ushort*)w; w += (size_t)256 * 64 * 2;
    ushort* wt2_lo    = (ushort*)w; w += (size_t)256 * 64 * 2;
    ushort* pbuf      = (ushort*)w; w += (size_t)N * 64 * 2;   // p, later a2
    ushort* qbuf      = (ushort*)w; w += (size_t)N * 64 * 2;   // q
    float*  rbuf      = (float*)w;  w += (size_t)N * 4;        // r = dinv*t

    hipMemsetAsync(cnt, 0, (size_t)N * 4 + 16, stream);   // cnt + total
    hipMemsetAsync(d_out, 0, sizeof(float), stream);

    const int tb = 256;
    wsplit_all_kernel<<<(64 * 512 + 64 * 256 + tb - 1) / tb, tb, 0, stream>>>(
        W1, W2, wt_hi, wt_lo, wt2_hi, wt2_lo);
    hist_kernel<<<(E + tb - 1) / tb, tb, 0, stream>>>(dstp, E, cnt, slot);
    alloc_kernel<<<(N + tb - 1) / tb, tb, 0, stream>>>(cnt, row_start, dinv, total, N);
    scatter_kernel<<<(E + tb - 1) / tb, tb, 0, stream>>>(src, dstp, E, row_start, slot, csr);

    // layer 1: p = dinv * (x @ W1) as bf16
    gemm1_kernel<<<(N + 127) / 128, 256, 0, stream>>>(x, wt_hi, wt_lo, dinv, pbuf, N);
    // q = dinv * relu(dinv * (p_self + sum p_nbr) + b1)
    agg64bf_kernel<1, 1, 1><<<(N + 3) / 4, 256, 0, stream>>>(pbuf, qbuf, row_start, cnt, csr, dinv, b1, N);
    // a2 = dinv * (q_self + sum q_nbr)   (reuses pbuf)
    agg64bf_kernel<0, 0, 0><<<(N + 3) / 4, 256, 0, stream>>>(qbuf, pbuf, row_start, cnt, csr, dinv, nullptr, N);

    // layers 2+3 fused via MFMA: r = dinv * (relu(a2 @ W2 + b2) @ W3)
    gemm23_kernel<<<(N + 127) / 128, 256, 0, stream>>>(pbuf, wt2_hi, wt2_lo, b2, W3, dinv, rbuf, N);

    // layer 3 aggregation (16-lane groups, grid-stride, 256 atomics) + BCE + mean
    loss_kernel<<<256, 1024, 0, stream>>>(rbuf, dinv, row_start, cnt, csr, y, b3,
                                          (float*)d_out, N, 1.0f / N);
}

// Round 5
// 605.846 us; speedup vs baseline: 1.5957x; 1.0351x over previous
//
#include <hip/hip_runtime.h>
#include <math.h>

typedef __attribute__((ext_vector_type(8))) short s16x8;   // 8 bf16 (4 VGPRs)
typedef __attribute__((ext_vector_type(4))) float f32x4;

__device__ inline ushort f2bf(float f) {
    union { float f; unsigned u; } v; v.f = f;
    unsigned r = v.u + 0x7FFF + ((v.u >> 16) & 1);   // RTN-even
    return (ushort)(r >> 16);
}
__device__ inline float bf2f(ushort h) {
    union { unsigned u; float f; } v; v.u = ((unsigned)h) << 16;
    return v.f;
}
__device__ inline float bfLo(unsigned u) {   // element at even index (low half)
    union { unsigned x; float f; } v; v.x = u << 16; return v.f;
}
__device__ inline float bfHi(unsigned u) {   // element at odd index (high half)
    union { unsigned x; float f; } v; v.x = u & 0xFFFF0000u; return v.f;
}

// ---------------- CSR build: 8-way privatized histogram + fused wsplit ----------------
// Edge-block b uses histogram copy b&7 (8x less same-address atomic contention).
// slot[e] = within-(copy,node) rank; scatter computes csr position from base8[g][d].
// Extra blocks past the edge range do the W1/W2 hi-lo split precompute.

__global__ void hist_wsplit_kernel(const int* __restrict__ dst, int E, int eb,
                                   int* __restrict__ cnt8, int N, int* __restrict__ slot,
                                   const float* __restrict__ W1, const float* __restrict__ W2,
                                   ushort* __restrict__ wt_hi, ushort* __restrict__ wt_lo,
                                   ushort* __restrict__ wt2_hi, ushort* __restrict__ wt2_lo) {
    int b = blockIdx.x;
    if (b < eb) {
        int e = b * 256 + threadIdx.x;
        if (e < E) {
            int g = b & 7;
            slot[e] = atomicAdd(&cnt8[(size_t)g * N + dst[e]], 1);
        }
        return;
    }
    int idx = (b - eb) * 256 + threadIdx.x;
    if (idx < 64 * 512) {
        int n = idx & 63, k = idx >> 6;           // read coalesced over n
        float f = W1[k * 64 + n];
        ushort h = f2bf(f);
        wt_hi[n * 512 + k] = h;
        wt_lo[n * 512 + k] = f2bf(f - bf2f(h));
    } else if (idx < 64 * 512 + 64 * 256) {
        int i2 = idx - 64 * 512;
        int n = i2 & 255, k = i2 >> 8;            // read coalesced over n
        float f = W2[k * 256 + n];
        ushort h = f2bf(f);
        wt2_hi[n * 64 + k] = h;
        wt2_lo[n * 64 + k] = f2bf(f - bf2f(h));
    }
}

// alloc: sum 8 histogram copies -> deg, row_start (wave scan + atomic), per-copy
// absolute bases base8[g][i], dinv. Also zeroes the loss output (kills a memset).
__global__ void alloc_kernel(const int* __restrict__ cnt8, int N,
                             int* __restrict__ row_start, int* __restrict__ base8,
                             int* __restrict__ deg, float* __restrict__ dinv,
                             int* __restrict__ total, float* __restrict__ out) {
    int i = blockIdx.x * blockDim.x + threadIdx.x;
    int lane = threadIdx.x & 63;
    int cg[8];
    int c = 0;
    if (i < N) {
#pragma unroll
        for (int g = 0; g < 8; g++) { cg[g] = cnt8[(size_t)g * N + i]; c += cg[g]; }
    } else {
#pragma unroll
        for (int g = 0; g < 8; g++) cg[g] = 0;
    }
    int inc = c;
#pragma unroll
    for (int o = 1; o < 64; o <<= 1) {
        int v = __shfl_up(inc, o, 64);
        if (lane >= o) inc += v;
    }
    int wsum = __shfl(inc, 63, 64);
    int base = 0;
    if (lane == 0) base = atomicAdd(total, wsum);
    base = __shfl(base, 0, 64);
    if (i < N) {
        int rs = base + inc - c;
        row_start[i] = rs;
        deg[i] = c;
        dinv[i] = rsqrtf((float)(c + 1));
        int run = rs;
#pragma unroll
        for (int g = 0; g < 8; g++) { base8[(size_t)g * N + i] = run; run += cg[g]; }
    }
    if (i == 0) *out = 0.f;
}

// ---------------- GEMM1 (MFMA) + fused atomic-free scatter ----------------
// Blocks [0, GB): p = dinv * (x @ W1) as bf16 (hi/lo 3-term split).
// Blocks [GB, GB+eb): csr[base8[g][d] + slot[e]] = src[e]  (g = edge-block & 7).
__global__ __launch_bounds__(256, 3) void gemm1_scatter_kernel(
        const float* __restrict__ x, const ushort* __restrict__ wt_hi,
        const ushort* __restrict__ wt_lo, const float* __restrict__ dinv,
        ushort* __restrict__ out, int N, int GB,
        const int* __restrict__ src, const int* __restrict__ dstp, int E,
        const int* __restrict__ base8, const int* __restrict__ slot,
        int* __restrict__ csr) {
    __shared__ __align__(16) short xs_hi[128 * 64];   // 16 KB  [node][g'*8+j]
    __shared__ __align__(16) short xs_lo[128 * 64];   // 16 KB
    __shared__ __align__(16) short ws_hi[64 * 64];    //  8 KB  [n][g'*8+j]
    __shared__ __align__(16) short ws_lo[64 * 64];    //  8 KB

    if ((int)blockIdx.x >= GB) {                      // scatter blocks
        int sb = (int)blockIdx.x - GB;
        int e = sb * 256 + threadIdx.x;
        if (e < E) {
            int d = dstp[e];
            int g = sb & 7;
            csr[base8[(size_t)g * N + d] + slot[e]] = src[e];
        }
        return;
    }

    const int tid = threadIdx.x;
    const int nodeBase = blockIdx.x * 128;
    const int wave = tid >> 6, lane = tid & 63;
    const int m16 = lane & 15, quad = lane >> 4;

    f32x4 acc[2][4];
#pragma unroll
    for (int mt = 0; mt < 2; mt++)
#pragma unroll
        for (int nt = 0; nt < 4; nt++) acc[mt][nt] = (f32x4){0.f, 0.f, 0.f, 0.f};

    for (int kc = 0; kc < 512; kc += 64) {
        __syncthreads();
#pragma unroll
        for (int i = 0; i < 4; i++) {
            int f = tid + i * 256;            // 0..1023
            int node = f >> 3, g = f & 7;
            int gn = nodeBase + node;
            if (gn >= N) gn = N - 1;
            const float4 a = *(const float4*)(x + (size_t)gn * 512 + kc + g * 8);
            const float4 b = *(const float4*)(x + (size_t)gn * 512 + kc + g * 8 + 4);
            float ff[8] = {a.x, a.y, a.z, a.w, b.x, b.y, b.z, b.w};
            union { ushort u[8]; uint4 v; } H, L;
#pragma unroll
            for (int j = 0; j < 8; j++) {
                ushort h = f2bf(ff[j]);
                H.u[j] = h;
                L.u[j] = f2bf(ff[j] - bf2f(h));
            }
            int gp = (g + node) & 7;
            *(uint4*)&xs_hi[node * 64 + gp * 8] = H.v;
            *(uint4*)&xs_lo[node * 64 + gp * 8] = L.v;
        }
#pragma unroll
        for (int i = 0; i < 2; i++) {
            int f = tid + i * 256;            // 0..511
            int n = f >> 3, g = f & 7;
            int gp = (g + n) & 7;
            *(uint4*)&ws_hi[n * 64 + gp * 8] =
                *(const uint4*)(wt_hi + (size_t)n * 512 + kc + g * 8);
            *(uint4*)&ws_lo[n * 64 + gp * 8] =
                *(const uint4*)(wt_lo + (size_t)n * 512 + kc + g * 8);
        }
        __syncthreads();
#pragma unroll
        for (int ck = 0; ck < 2; ck++) {
            s16x8 Ah[2], Al[2];
#pragma unroll
            for (int mt = 0; mt < 2; mt++) {
                int row = (wave * 2 + mt) * 16 + m16;     // local 0..127
                int gp = (ck * 4 + quad + row) & 7;
                Ah[mt] = *(s16x8*)&xs_hi[row * 64 + gp * 8];
                Al[mt] = *(s16x8*)&xs_lo[row * 64 + gp * 8];
            }
#pragma unroll
            for (int nt = 0; nt < 4; nt++) {
                int n = nt * 16 + m16;                    // local 0..63
                int gp = (ck * 4 + quad + n) & 7;
                s16x8 Bh = *(s16x8*)&ws_hi[n * 64 + gp * 8];
                s16x8 Bl = *(s16x8*)&ws_lo[n * 64 + gp * 8];
#pragma unroll
                for (int mt = 0; mt < 2; mt++) {
                    acc[mt][nt] = __builtin_amdgcn_mfma_f32_16x16x32_bf16(Ah[mt], Bh, acc[mt][nt], 0, 0, 0);
                    acc[mt][nt] = __builtin_amdgcn_mfma_f32_16x16x32_bf16(Ah[mt], Bl, acc[mt][nt], 0, 0, 0);
                    acc[mt][nt] = __builtin_amdgcn_mfma_f32_16x16x32_bf16(Al[mt], Bh, acc[mt][nt], 0, 0, 0);
                }
            }
        }
    }
    // C/D layout: col = lane&15, row = quad*4 + reg. Write p = dinv*acc as bf16.
#pragma unroll
    for (int mt = 0; mt < 2; mt++) {
#pragma unroll
        for (int r = 0; r < 4; r++) {
            int gn = nodeBase + (wave * 2 + mt) * 16 + quad * 4 + r;
            if (gn < N) {
                float di = dinv[gn];
#pragma unroll
                for (int nt = 0; nt < 4; nt++)
                    out[(size_t)gn * 64 + nt * 16 + m16] = f2bf(di * acc[mt][nt][r]);
            }
        }
    }
}

// ---------------- 64-dim CSR aggregation, vectorized: 4 rows per wave-instruction -------
// out[i] = post( dinv[i] * (in[i] + sum_j in[j]) ), one wave per node.
// Lane layout: quad = lane>>4 handles neighbor slot e+quad; 16 lanes cover the full
// 128 B row with uint2 (4 bf16 each). Slot 0 = self loop. Two batches in flight.
template <int RELU, int BIAS, int PREMUL>
__global__ void agg64bf_kernel(const ushort* __restrict__ in, ushort* __restrict__ out,
                               const int* __restrict__ row_start, const int* __restrict__ deg,
                               const int* __restrict__ csr, const float* __restrict__ dinv,
                               const float* __restrict__ bias, int N) {
    int gw = (int)((blockIdx.x * (size_t)blockDim.x + threadIdx.x) >> 6);
    int lane = threadIdx.x & 63;
    if (gw >= N) return;
    const int m16 = lane & 15;        // feature group: features 4*m16 .. 4*m16+3
    const int quad = lane >> 4;       // neighbor slot within the batch of 4

    const int s = row_start[gw];
    const int c = deg[gw];
    const int total = c + 1;          // slot 0 = self, slots 1..c = neighbors

    float a0 = 0.f, a1 = 0.f, a2v = 0.f, a3 = 0.f;
    for (int e = 0; e < total; e += 8) {
        int s0 = e + quad, s1 = e + 4 + quad;
        bool v0 = s0 < total, v1 = s1 < total;
        int j0 = gw, j1 = gw;
        if (v0 && s0 > 0) j0 = csr[s + s0 - 1];
        if (v1 && s1 > 0) j1 = csr[s + s1 - 1];
        uint2 u0 = *(const uint2*)(in + (size_t)j0 * 64 + m16 * 4);
        uint2 u1 = *(const uint2*)(in + (size_t)j1 * 64 + m16 * 4);
        if (v0) { a0 += bfLo(u0.x); a1 += bfHi(u0.x); a2v += bfLo(u0.y); a3 += bfHi(u0.y); }
        if (v1) { a0 += bfLo(u1.x); a1 += bfHi(u1.x); a2v += bfLo(u1.y); a3 += bfHi(u1.y); }
    }
    // combine the 4 quads (lane ^16, ^32)
    a0 += __shfl_xor(a0, 16, 64); a0 += __shfl_xor(a0, 32, 64);
    a1 += __shfl_xor(a1, 16, 64); a1 += __shfl_xor(a1, 32, 64);
    a2v += __shfl_xor(a2v, 16, 64); a2v += __shfl_xor(a2v, 32, 64);
    a3 += __shfl_xor(a3, 16, 64); a3 += __shfl_xor(a3, 32, 64);

    float di = dinv[gw];
    float r0 = di * a0, r1 = di * a1, r2 = di * a2v, r3 = di * a3;
    if (BIAS) {
        float4 bv = *(const float4*)&bias[m16 * 4];
        r0 += bv.x; r1 += bv.y; r2 += bv.z; r3 += bv.w;
    }
    if (RELU) {
        r0 = fmaxf(r0, 0.f); r1 = fmaxf(r1, 0.f);
        r2 = fmaxf(r2, 0.f); r3 = fmaxf(r3, 0.f);
    }
    if (PREMUL) { r0 *= di; r1 *= di; r2 *= di; r3 *= di; }
    if (quad == 0) {
        uint2 o;
        o.x = ((unsigned)f2bf(r1) << 16) | f2bf(r0);
        o.y = ((unsigned)f2bf(r3) << 16) | f2bf(r2);
        *(uint2*)(out + (size_t)gw * 64 + m16 * 4) = o;
    }
}

// ---------------- fused GEMM2 (+bias,relu) + GEMM3, MFMA version ----------------
// r[i] = dinv[i] * (relu(a2[i] @ W2 + b2) @ W3)
// a2 is ALREADY bf16 (exact A operand). W2 split into bf16 hi/lo (2-term).
// Fragments loaded directly from global; no LDS, no barriers. W2^T hi/lo L2-resident.
__global__ __launch_bounds__(256, 2) void gemm23_kernel(const ushort* __restrict__ a2,
                                                        const ushort* __restrict__ wt2_hi,
                                                        const ushort* __restrict__ wt2_lo,
                                                        const float* __restrict__ b2,
                                                        const float* __restrict__ W3,
                                                        const float* __restrict__ dinv,
                                                        float* __restrict__ r, int N) {
    const int tid = threadIdx.x;
    const int wave = tid >> 6, lane = tid & 63;
    const int m16 = lane & 15, quad = lane >> 4;
    const int rowBase = blockIdx.x * 128 + wave * 32;   // wave covers 32 nodes

    // A fragments: row = rowBase + mt*16 + m16, k = ck*32 + quad*8 .. +8
    s16x8 A[2][2];
#pragma unroll
    for (int mt = 0; mt < 2; mt++) {
        int gn = rowBase + mt * 16 + m16;
        if (gn >= N) gn = N - 1;
        const ushort* ap = a2 + (size_t)gn * 64 + quad * 8;
#pragma unroll
        for (int ck = 0; ck < 2; ck++)
            A[mt][ck] = *(const s16x8*)(ap + ck * 32);
    }

    f32x4 acc[2][16];
#pragma unroll
    for (int mt = 0; mt < 2; mt++)
#pragma unroll
        for (int nt = 0; nt < 16; nt++) acc[mt][nt] = (f32x4){0.f, 0.f, 0.f, 0.f};

#pragma unroll
    for (int nt = 0; nt < 16; nt++) {
        int n = nt * 16 + m16;                           // output col 0..255
        const ushort* bh = wt2_hi + (size_t)n * 64 + quad * 8;
        const ushort* bl = wt2_lo + (size_t)n * 64 + quad * 8;
        s16x8 Bh0 = *(const s16x8*)(bh);
        s16x8 Bh1 = *(const s16x8*)(bh + 32);
        s16x8 Bl0 = *(const s16x8*)(bl);
        s16x8 Bl1 = *(const s16x8*)(bl + 32);
        acc[0][nt] = __builtin_amdgcn_mfma_f32_16x16x32_bf16(A[0][0], Bh0, acc[0][nt], 0, 0, 0);
        acc[1][nt] = __builtin_amdgcn_mfma_f32_16x16x32_bf16(A[1][0], Bh0, acc[1][nt], 0, 0, 0);
        acc[0][nt] = __builtin_amdgcn_mfma_f32_16x16x32_bf16(A[0][1], Bh1, acc[0][nt], 0, 0, 0);
        acc[1][nt] = __builtin_amdgcn_mfma_f32_16x16x32_bf16(A[1][1], Bh1, acc[1][nt], 0, 0, 0);
        acc[0][nt] = __builtin_amdgcn_mfma_f32_16x16x32_bf16(A[0][0], Bl0, acc[0][nt], 0, 0, 0);
        acc[1][nt] = __builtin_amdgcn_mfma_f32_16x16x32_bf16(A[1][0], Bl0, acc[1][nt], 0, 0, 0);
        acc[0][nt] = __builtin_amdgcn_mfma_f32_16x16x32_bf16(A[0][1], Bl1, acc[0][nt], 0, 0, 0);
        acc[1][nt] = __builtin_amdgcn_mfma_f32_16x16x32_bf16(A[1][1], Bl1, acc[1][nt], 0, 0, 0);
    }

    // epilogue: per lane holds cols {nt*16+m16} of rows {mt*16+quad*4+rr}
    float bv[16], wv[16];
#pragma unroll
    for (int nt = 0; nt < 16; nt++) {
        bv[nt] = b2[nt * 16 + m16];
        wv[nt] = W3[nt * 16 + m16];
    }
#pragma unroll
    for (int mt = 0; mt < 2; mt++) {
#pragma unroll
        for (int rr = 0; rr < 4; rr++) {
            float p = 0.f;
#pragma unroll
            for (int nt = 0; nt < 16; nt++) {
                float v = fmaxf(acc[mt][nt][rr] + bv[nt], 0.f);
                p = fmaf(v, wv[nt], p);
            }
            // reduce the 16-lane m16 group (same quad = same row)
#pragma unroll
            for (int off = 1; off < 16; off <<= 1) p += __shfl_xor(p, off, 64);
            int gn = rowBase + mt * 16 + quad * 4 + rr;
            if (m16 == 0 && gn < N) r[gn] = dinv[gn] * p;
        }
    }
}

// ---------------- loss: 16-lane-group-per-node gather + BCE, few atomics ----------------
// Grid-stride over nodes; 4 nodes per wave; block-level LDS reduce -> 1 atomic/block.
__global__ __launch_bounds__(1024) void loss_kernel(const float* __restrict__ r,
                                                    const float* __restrict__ dinv,
                                                    const int* __restrict__ row_start,
                                                    const int* __restrict__ deg,
                                                    const int* __restrict__ csr,
                                                    const float* __restrict__ y,
                                                    const float* __restrict__ b3,
                                                    float* __restrict__ out,
                                                    int N, float invN) {
    const int lane = threadIdx.x & 63;
    const int wave = threadIdx.x >> 6;       // 0..15
    const int l16 = lane & 15;
    const int grp = lane >> 4;               // 0..3: node slot within wave
    const int waveId = blockIdx.x * 16 + wave;
    const int nWaves = gridDim.x * 16;
    const float b3v = b3[0];

    float loss = 0.f;
    for (int base = waveId * 4; base < N; base += nWaves * 4) {
        int node = base + grp;
        float acc = 0.f;
        if (node < N) {
            int s = row_start[node], c = deg[node];
            for (int e = l16; e < c; e += 16) acc += r[csr[s + e]];
        }
        // reduce within the 16-lane group
        acc += __shfl_xor(acc, 1, 64);
        acc += __shfl_xor(acc, 2, 64);
        acc += __shfl_xor(acc, 4, 64);
        acc += __shfl_xor(acc, 8, 64);
        if (node < N && l16 == 0) {
            float z = dinv[node] * (r[node] + acc) + b3v;
            float yv = y[node];
            float L = log1pf(expf(-fabsf(z)));
            float spz  = fmaxf(z, 0.f) + L;    // softplus(z)
            float spnz = fmaxf(-z, 0.f) + L;   // softplus(-z)
            loss += yv * spnz + (1.f - yv) * spz;
        }
    }
#pragma unroll
    for (int off = 1; off < 64; off <<= 1) loss += __shfl_xor(loss, off, 64);
    __shared__ float red[16];
    if (lane == 0) red[wave] = loss;
    __syncthreads();
    if (threadIdx.x == 0) {
        float t = 0.f;
#pragma unroll
        for (int i = 0; i < 16; i++) t += red[i];
        atomicAdd(out, t * invN);
    }
}

// ---------------- launch ----------------
extern "C" void kernel_launch(void* const* d_in, const int* in_sizes, int n_in,
                              void* d_out, int out_size, void* d_ws, size_t ws_size,
                              hipStream_t stream) {
    const float* x  = (const float*)d_in[0];
    const int*   ei = (const int*)d_in[1];
    const float* y  = (const float*)d_in[2];
    const float* W1 = (const float*)d_in[3];
    const float* b1 = (const float*)d_in[4];
    const float* W2 = (const float*)d_in[5];
    const float* b2 = (const float*)d_in[6];
    const float* W3 = (const float*)d_in[7];
    const float* b3 = (const float*)d_in[8];

    const int N = in_sizes[2];        // y has N elements
    const int E = in_sizes[1] / 2;
    const int* src  = ei;
    const int* dstp = ei + E;

    char* w = (char*)d_ws;
    int*    cnt8      = (int*)w;    w += (size_t)8 * N * 4;
    int*    total     = (int*)w;    w += 16;
    int*    row_start = (int*)w;    w += (size_t)N * 4;
    int*    deg       = (int*)w;    w += (size_t)N * 4;
    float*  dinv      = (float*)w;  w += (size_t)N * 4;
    int*    base8     = (int*)w;    w += (size_t)8 * N * 4;
    int*    csr       = (int*)w;    w += (size_t)E * 4;
    int*    slot      = (int*)w;    w += (size_t)E * 4;
    ushort* wt_hi     = (ushort*)w; w += (size_t)64 * 512 * 2;
    ushort* wt_lo     = (ushort*)w; w += (size_t)64 * 512 * 2;
    ushort* wt2_hi    = (ushort*)w; w += (size_t)256 * 64 * 2;
    ushort* wt2_lo    = (ushort*)w; w += (size_t)256 * 64 * 2;
    ushort* pbuf      = (ushort*)w; w += (size_t)N * 64 * 2;   // p, later a2
    ushort* qbuf      = (ushort*)w; w += (size_t)N * 64 * 2;   // q
    float*  rbuf      = (float*)w;  w += (size_t)N * 4;        // r = dinv*t

    hipMemsetAsync(cnt8, 0, (size_t)8 * N * 4 + 16, stream);   // cnt8 + total

    const int tb = 256;
    const int eb = (E + tb - 1) / tb;                      // edge blocks
    const int wb = (64 * 512 + 64 * 256 + tb - 1) / tb;    // wsplit blocks
    const int GB = (N + 127) / 128;                        // gemm1 blocks

    // histogram (8-way privatized) + W-split precompute, one dispatch
    hist_wsplit_kernel<<<eb + wb, tb, 0, stream>>>(dstp, E, eb, cnt8, N, slot,
                                                   W1, W2, wt_hi, wt_lo, wt2_hi, wt2_lo);
    // degree/row_start/base8/dinv + zero d_out
    alloc_kernel<<<(N + tb - 1) / tb, tb, 0, stream>>>(cnt8, N, row_start, base8, deg, dinv,
                                                       total, (float*)d_out);
    // layer 1 GEMM + atomic-free CSR scatter, one dispatch
    gemm1_scatter_kernel<<<GB + eb, 256, 0, stream>>>(x, wt_hi, wt_lo, dinv, pbuf, N, GB,
                                                      src, dstp, E, base8, slot, csr);
    // q = dinv * relu(dinv * (p_self + sum p_nbr) + b1)
    agg64bf_kernel<1, 1, 1><<<(N + 3) / 4, 256, 0, stream>>>(pbuf, qbuf, row_start, deg, csr, dinv, b1, N);
    // a2 = dinv * (q_self + sum q_nbr)   (reuses pbuf)
    agg64bf_kernel<0, 0, 0><<<(N + 3) / 4, 256, 0, stream>>>(qbuf, pbuf, row_start, deg, csr, dinv, nullptr, N);

    // layers 2+3 fused via MFMA: r = dinv * (relu(a2 @ W2 + b2) @ W3)
    gemm23_kernel<<<(N + 127) / 128, 256, 0, stream>>>(pbuf, wt2_hi, wt2_lo, b2, W3, dinv, rbuf, N);

    // layer 3 aggregation (16-lane groups, grid-stride, 256 atomics) + BCE + mean
    loss_kernel<<<256, 1024, 0, stream>>>(rbuf, dinv, row_start, deg, csr, y, b3,
                                          (float*)d_out, N, 1.0f / N);
}